// Round 1
// baseline (696.818 us; speedup 1.0000x reference)
//
#include <hip/hip_runtime.h>

#define N_NODES 100000
#define E_EDGES 3200000
#define IN_CH 256
#define HID 32
#define OUT_CH 16

// ---------------- graph preprocessing ----------------

__global__ void k_deg(const int* __restrict__ col, int* __restrict__ deg, int e_cnt) {
    int e = blockIdx.x * blockDim.x + threadIdx.x;
    if (e < e_cnt) atomicAdd(&deg[col[e]], 1);
}

__global__ void k_dis(const int* __restrict__ deg, float* __restrict__ dis,
                      int* __restrict__ start, int* __restrict__ cursor,
                      int* __restrict__ counter, int n) {
    int v = blockIdx.x * blockDim.x + threadIdx.x;
    if (v < n) {
        int d = deg[v];
        dis[v] = rsqrtf((float)(d + 1));   // +1 self loop
        int s = atomicAdd(counter, d);     // segment allocation (order-free)
        start[v] = s;
        cursor[v] = s;
    }
}

__global__ void k_scatter(const int* __restrict__ row, const int* __restrict__ col,
                          int* __restrict__ cursor, int* __restrict__ srow, int e_cnt) {
    int e = blockIdx.x * blockDim.x + threadIdx.x;
    if (e < e_cnt) {
        int c = col[e];
        int pos = atomicAdd(&cursor[c], 1);
        srow[pos] = row[e];
    }
}

// ---------------- layer 1 GEMM: h0 = x @ W1  [N,256]x[256,32] ----------------

__global__ void k_gemm1(const float* __restrict__ x, const float* __restrict__ W1,
                        float* __restrict__ h0, int n) {
    int v = blockIdx.x * blockDim.x + threadIdx.x;
    if (v >= n) return;
    const float* xr = x + (size_t)v * IN_CH;
    float acc[HID];
#pragma unroll
    for (int c = 0; c < HID; ++c) acc[c] = 0.0f;
    for (int k = 0; k < IN_CH; k += 4) {
        float4 xv = *reinterpret_cast<const float4*>(xr + k);
        float xs[4] = {xv.x, xv.y, xv.z, xv.w};
#pragma unroll
        for (int j = 0; j < 4; ++j) {
#pragma unroll
            for (int c = 0; c < HID; ++c)
                acc[c] = fmaf(xs[j], W1[(k + j) * HID + c], acc[c]);  // W1 idx wave-uniform -> s_load
        }
    }
    float4* o = reinterpret_cast<float4*>(h0 + (size_t)v * HID);
#pragma unroll
    for (int q = 0; q < HID / 4; ++q)
        o[q] = make_float4(acc[q * 4 + 0], acc[q * 4 + 1], acc[q * 4 + 2], acc[q * 4 + 3]);
}

// ---------------- aggregation 1 (pull) + bias + relu ----------------

__global__ void k_agg1(const float* __restrict__ h0, const int* __restrict__ srow,
                       const int* __restrict__ start, const int* __restrict__ deg,
                       const float* __restrict__ dis, const float* __restrict__ b1,
                       float* __restrict__ h, int n) {
    int v = blockIdx.x * (blockDim.x >> 5) + (threadIdx.x >> 5);
    int c = threadIdx.x & 31;
    if (v >= n) return;
    int s = start[v];
    int d = deg[v];
    float a0 = 0.f, a1 = 0.f, a2 = 0.f, a3 = 0.f;
    int i = 0;
    for (; i + 4 <= d; i += 4) {
        int u0 = srow[s + i + 0];
        int u1 = srow[s + i + 1];
        int u2 = srow[s + i + 2];
        int u3 = srow[s + i + 3];
        a0 = fmaf(dis[u0], h0[(size_t)u0 * HID + c], a0);
        a1 = fmaf(dis[u1], h0[(size_t)u1 * HID + c], a1);
        a2 = fmaf(dis[u2], h0[(size_t)u2 * HID + c], a2);
        a3 = fmaf(dis[u3], h0[(size_t)u3 * HID + c], a3);
    }
    for (; i < d; ++i) {
        int u = srow[s + i];
        a0 = fmaf(dis[u], h0[(size_t)u * HID + c], a0);
    }
    float acc = (a0 + a1) + (a2 + a3);
    float dv = dis[v];
    float val = fmaf(dv, acc, dv * dv * h0[(size_t)v * HID + c]) + b1[c];
    h[(size_t)v * HID + c] = fmaxf(val, 0.0f);
}

// ---------------- layer 2+3 GEMM: t = h @ [Wmu | Wlv]  [N,32]x[32,32] ----------------

__global__ void k_gemm2(const float* __restrict__ h, const float* __restrict__ Wmu,
                        const float* __restrict__ Wlv, float* __restrict__ t, int n) {
    int v = blockIdx.x * blockDim.x + threadIdx.x;
    if (v >= n) return;
    const float* hr = h + (size_t)v * HID;
    float hreg[HID];
#pragma unroll
    for (int q = 0; q < HID / 4; ++q) {
        float4 hv = reinterpret_cast<const float4*>(hr)[q];
        hreg[q * 4 + 0] = hv.x; hreg[q * 4 + 1] = hv.y;
        hreg[q * 4 + 2] = hv.z; hreg[q * 4 + 3] = hv.w;
    }
    float am[OUT_CH], al[OUT_CH];
#pragma unroll
    for (int c = 0; c < OUT_CH; ++c) { am[c] = 0.f; al[c] = 0.f; }
#pragma unroll
    for (int k = 0; k < HID; ++k) {
#pragma unroll
        for (int c = 0; c < OUT_CH; ++c) {
            am[c] = fmaf(hreg[k], Wmu[k * OUT_CH + c], am[c]);
            al[c] = fmaf(hreg[k], Wlv[k * OUT_CH + c], al[c]);
        }
    }
    float* tr = t + (size_t)v * HID;
    float4* o = reinterpret_cast<float4*>(tr);
#pragma unroll
    for (int q = 0; q < OUT_CH / 4; ++q)
        o[q] = make_float4(am[q * 4], am[q * 4 + 1], am[q * 4 + 2], am[q * 4 + 3]);
#pragma unroll
    for (int q = 0; q < OUT_CH / 4; ++q)
        o[OUT_CH / 4 + q] = make_float4(al[q * 4], al[q * 4 + 1], al[q * 4 + 2], al[q * 4 + 3]);
}

// ---------------- aggregation 2 (pull) -> mu, logvar ----------------

__global__ void k_agg2(const float* __restrict__ t, const int* __restrict__ srow,
                       const int* __restrict__ start, const int* __restrict__ deg,
                       const float* __restrict__ dis, const float* __restrict__ bmu,
                       const float* __restrict__ blv, float* __restrict__ out, int n) {
    int v = blockIdx.x * (blockDim.x >> 5) + (threadIdx.x >> 5);
    int c = threadIdx.x & 31;
    if (v >= n) return;
    int s = start[v];
    int d = deg[v];
    float a0 = 0.f, a1 = 0.f, a2 = 0.f, a3 = 0.f;
    int i = 0;
    for (; i + 4 <= d; i += 4) {
        int u0 = srow[s + i + 0];
        int u1 = srow[s + i + 1];
        int u2 = srow[s + i + 2];
        int u3 = srow[s + i + 3];
        a0 = fmaf(dis[u0], t[(size_t)u0 * HID + c], a0);
        a1 = fmaf(dis[u1], t[(size_t)u1 * HID + c], a1);
        a2 = fmaf(dis[u2], t[(size_t)u2 * HID + c], a2);
        a3 = fmaf(dis[u3], t[(size_t)u3 * HID + c], a3);
    }
    for (; i < d; ++i) {
        int u = srow[s + i];
        a0 = fmaf(dis[u], t[(size_t)u * HID + c], a0);
    }
    float acc = (a0 + a1) + (a2 + a3);
    float dv = dis[v];
    float self = t[(size_t)v * HID + c];
    float bias = (c < OUT_CH) ? bmu[c] : blv[c - OUT_CH];
    float val = fmaf(dv, acc, dv * dv * self) + bias;
    if (c < OUT_CH)
        out[(size_t)v * OUT_CH + c] = val;
    else
        out[(size_t)N_NODES * OUT_CH + (size_t)v * OUT_CH + (c - OUT_CH)] = val;
}

// ---------------- launch ----------------

extern "C" void kernel_launch(void* const* d_in, const int* in_sizes, int n_in,
                              void* d_out, int out_size, void* d_ws, size_t ws_size,
                              hipStream_t stream) {
    const float* x   = (const float*)d_in[0];
    const int*   ei  = (const int*)d_in[1];
    const float* W1  = (const float*)d_in[2];
    const float* b1  = (const float*)d_in[3];
    const float* Wmu = (const float*)d_in[4];
    const float* bmu = (const float*)d_in[5];
    const float* Wlv = (const float*)d_in[6];
    const float* blv = (const float*)d_in[7];
    float* out = (float*)d_out;

    const int* row = ei;            // edge_index[0]
    const int* col = ei + E_EDGES;  // edge_index[1]

    char* w = (char*)d_ws;
    int*   deg     = (int*)w;    w += (size_t)N_NODES * 4;
    int*   counter = (int*)w;    w += 64;  // aligned slot
    float* dis     = (float*)w;  w += (size_t)N_NODES * 4;
    int*   start   = (int*)w;    w += (size_t)N_NODES * 4;
    int*   cursor  = (int*)w;    w += (size_t)N_NODES * 4;
    int*   srow    = (int*)w;    w += (size_t)E_EDGES * 4;
    float* h0      = (float*)w;  w += (size_t)N_NODES * HID * 4;
    float* h       = (float*)w;  w += (size_t)N_NODES * HID * 4;
    float* t       = h0;  // reuse: h0 dead after k_agg1

    // zero deg + counter (deterministic every launch)
    hipMemsetAsync(deg, 0, (size_t)N_NODES * 4 + 64, stream);

    const int TB = 256;
    k_deg<<<(E_EDGES + TB - 1) / TB, TB, 0, stream>>>(col, deg, E_EDGES);
    k_dis<<<(N_NODES + TB - 1) / TB, TB, 0, stream>>>(deg, dis, start, cursor, counter, N_NODES);
    k_scatter<<<(E_EDGES + TB - 1) / TB, TB, 0, stream>>>(row, col, cursor, srow, E_EDGES);
    k_gemm1<<<(N_NODES + TB - 1) / TB, TB, 0, stream>>>(x, W1, h0, N_NODES);
    k_agg1<<<(N_NODES + 7) / 8, TB, 0, stream>>>(h0, srow, start, deg, dis, b1, h, N_NODES);
    k_gemm2<<<(N_NODES + TB - 1) / TB, TB, 0, stream>>>(h, Wmu, Wlv, t, N_NODES);
    k_agg2<<<(N_NODES + 7) / 8, TB, 0, stream>>>(t, srow, start, deg, dis, bmu, blv, out, N_NODES);
}